// Round 5
// baseline (3143.175 us; speedup 1.0000x reference)
//
#include <hip/hip_runtime.h>
#include <hip/hip_bf16.h>
#include <math.h>

constexpr int NN = 100000;     // nodes
constexpr int NE = 3200000;    // edges
constexpr int HID = 256;
constexpr int NBLK = (NN + 255) / 256;   // 391

typedef __attribute__((ext_vector_type(8))) short short8;
typedef __attribute__((ext_vector_type(4))) float floatx4;
typedef __attribute__((ext_vector_type(8))) unsigned short ushort8v;

// ---- bf16 helpers (storage bf16, math fp32) -------------------------------
__device__ __forceinline__ float bf2f(unsigned short u) {
    unsigned int t = ((unsigned int)u) << 16;
    float f; __builtin_memcpy(&f, &t, 4); return f;
}
__device__ __forceinline__ unsigned short f2bf(float f) {
    unsigned int t; __builtin_memcpy(&t, &f, 4);
    unsigned int lsb = (t >> 16) & 1u;
    t += 0x7fffu + lsb;
    return (unsigned short)(t >> 16);
}

// async global->LDS, 16B per lane; lds base must be wave-uniform
__device__ __forceinline__ void llds16(const void* g, void* l) {
    __builtin_amdgcn_global_load_lds(
        (const __attribute__((address_space(1))) unsigned int*)g,
        (__attribute__((address_space(3))) unsigned int*)l, 16, 0, 0);
}

// ---------------------------------------------------------------------------
// Edge dtype detection (int64 vs int32 delivery)
// ---------------------------------------------------------------------------
__global__ void detect_i64(const int* __restrict__ ei, int* __restrict__ flag) {
    if (blockIdx.x == 0 && threadIdx.x == 0) {
        int z = 1;
        for (int i = 0; i < 64; ++i)
            if (ei[2 * i + 1] != 0) { z = 0; break; }
        *flag = z;
    }
}
__device__ __forceinline__ int load_edge(const int* ei, int is64, long long idx) {
    if (is64) return (int)(((const long long*)ei)[idx]);
    return ei[idx];
}

__global__ void zero_setup(int* __restrict__ cnt, int* __restrict__ cursor,
                           float* __restrict__ gsum) {
    int i = blockIdx.x * 256 + threadIdx.x;
    if (i < NN) { cnt[i] = 0; cursor[i] = 0; }
    if (i < HID) gsum[i] = 0.0f;
}

// ---------------------------------------------------------------------------
// Weight / input conversion to bf16
// ---------------------------------------------------------------------------
__global__ void conv_weights(const float* __restrict__ Wf, const float* __restrict__ Uf,
                             const float* __restrict__ Wh, const float* __restrict__ Uh,
                             const float* __restrict__ Win,
                             unsigned short* __restrict__ wcf,
                             unsigned short* __restrict__ wch,
                             unsigned short* __restrict__ wib) {
    int i = blockIdx.x * 256 + threadIdx.x;
    if (i < 256 * 512) {
        int n = i >> 9, k = i & 511;
        float vf = (k < 256) ? Wf[n * 256 + k] : Uf[n * 256 + k - 256];
        float vh = (k < 256) ? Wh[n * 256 + k] : Uh[n * 256 + k - 256];
        wcf[i] = f2bf(vf); wch[i] = f2bf(vh);
    }
    if (i < 128 * 128) wib[i] = f2bf(Win[i]);
}

__global__ void conv_x(const float* __restrict__ x, unsigned short* __restrict__ xb) {
    int i = blockIdx.x * 256 + threadIdx.x;
    if (i < NN * 128 / 4) {
        float4 v = ((const float4*)x)[i];
        ushort4 o;
        o.x = f2bf(v.x); o.y = f2bf(v.y); o.z = f2bf(v.z); o.w = f2bf(v.w);
        ((ushort4*)xb)[i] = o;
    }
}

// ---------------------------------------------------------------------------
// CSR construction
// ---------------------------------------------------------------------------
__global__ void count_deg(const int* __restrict__ ei, const int* __restrict__ flag,
                          int* __restrict__ cnt) {
    int e = blockIdx.x * 256 + threadIdx.x;
    if (e >= NE) return;
    int is64 = *flag;
    int d = load_edge(ei, is64, (long long)NE + e);
    d = min(max(d, 0), NN - 1);
    atomicAdd(&cnt[d], 1);
}

__global__ void scan_k1(const int* __restrict__ cnt, int* __restrict__ loc,
                        int* __restrict__ bsum) {
    __shared__ int s[256];
    int b = blockIdx.x, t = threadIdx.x;
    int i = b * 256 + t;
    int v = (i < NN) ? cnt[i] : 0;
    s[t] = v;
    __syncthreads();
    for (int ofs = 1; ofs < 256; ofs <<= 1) {
        int tv = (t >= ofs) ? s[t - ofs] : 0;
        __syncthreads();
        s[t] += tv;
        __syncthreads();
    }
    if (i < NN) loc[i] = s[t] - v;
    if (t == 255) bsum[b] = s[255];
}
__global__ void scan_k2(const int* __restrict__ bsum, int* __restrict__ bpre) {
    __shared__ int s[512];
    int t = threadIdx.x;
    int v = (t < NBLK) ? bsum[t] : 0;
    s[t] = v;
    __syncthreads();
    for (int ofs = 1; ofs < 512; ofs <<= 1) {
        int tv = (t >= ofs) ? s[t - ofs] : 0;
        __syncthreads();
        s[t] += tv;
        __syncthreads();
    }
    if (t < NBLK) bpre[t] = s[t] - v;
    if (t == NBLK - 1) bpre[NBLK] = s[t];
}
__global__ void scan_k3(const int* __restrict__ loc, const int* __restrict__ bpre,
                        int* __restrict__ off) {
    int b = blockIdx.x, t = threadIdx.x;
    int i = b * 256 + t;
    if (i < NN) off[i] = loc[i] + bpre[b];
    if (b == 0 && t == 0) off[NN] = bpre[NBLK];
}

__global__ void fill_csr(const int* __restrict__ ei, const int* __restrict__ flag,
                         const int* __restrict__ off, int* __restrict__ cursor,
                         int* __restrict__ csr) {
    int e = blockIdx.x * 256 + threadIdx.x;
    if (e >= NE) return;
    int is64 = *flag;
    int s = load_edge(ei, is64, e);
    int d = load_edge(ei, is64, (long long)NE + e);
    s = min(max(s, 0), NN - 1);
    d = min(max(d, 0), NN - 1);
    int p = atomicAdd(&cursor[d], 1);
    csr[off[d] + p] = s;
}

// ---------------------------------------------------------------------------
// Aggregation: mean of h[src] rows per node. One wave per node; half-wave per
// edge row (ushort8/lane), 4 rows in flight.
// ---------------------------------------------------------------------------
__global__ __launch_bounds__(256)
void aggregate(const unsigned short* __restrict__ h, const int* __restrict__ off,
               const int* __restrict__ csr, unsigned short* __restrict__ m) {
    int node = blockIdx.x * 4 + (threadIdx.x >> 6);
    int lane = threadIdx.x & 63;
    int half = lane >> 5;
    int fl = lane & 31;
    int e0 = off[node], e1 = off[node + 1];
    float a0[8], a1[8];
#pragma unroll
    for (int k = 0; k < 8; ++k) { a0[k] = 0.f; a1[k] = 0.f; }
    int e = e0;
    for (; e + 8 <= e1; e += 8) {
        int s0 = csr[e + half];
        int s1 = csr[e + 2 + half];
        int s2 = csr[e + 4 + half];
        int s3 = csr[e + 6 + half];
        ushort8v v0 = *(const ushort8v*)(h + (size_t)s0 * HID + fl * 8);
        ushort8v v1 = *(const ushort8v*)(h + (size_t)s1 * HID + fl * 8);
        ushort8v v2 = *(const ushort8v*)(h + (size_t)s2 * HID + fl * 8);
        ushort8v v3 = *(const ushort8v*)(h + (size_t)s3 * HID + fl * 8);
#pragma unroll
        for (int k = 0; k < 8; ++k) {
            a0[k] += bf2f(v0[k]); a1[k] += bf2f(v1[k]);
            a0[k] += bf2f(v2[k]); a1[k] += bf2f(v3[k]);
        }
    }
    for (; e + 2 <= e1; e += 2) {
        int s0 = csr[e + half];
        ushort8v v0 = *(const ushort8v*)(h + (size_t)s0 * HID + fl * 8);
#pragma unroll
        for (int k = 0; k < 8; ++k) a0[k] += bf2f(v0[k]);
    }
    if (e < e1 && half == 0) {
        int s0 = csr[e];
        ushort8v v0 = *(const ushort8v*)(h + (size_t)s0 * HID + fl * 8);
#pragma unroll
        for (int k = 0; k < 8; ++k) a0[k] += bf2f(v0[k]);
    }
#pragma unroll
    for (int k = 0; k < 8; ++k) a0[k] += a1[k];
#pragma unroll
    for (int k = 0; k < 8; ++k) a0[k] += __shfl(a0[k], lane ^ 32, 64);
    float inv = 1.0f / (float)max(e1 - e0, 1);
    if (half == 0) {
        ushort8v o;
#pragma unroll
        for (int k = 0; k < 8; ++k) o[k] = f2bf(a0[k] * inv);
        *(ushort8v*)(m + (size_t)node * HID + fl * 8) = o;
    }
}

// ---------------------------------------------------------------------------
// Input-encode MFMA GEMM (K=128): h = relu(x @ W_in^T + b_in), pad to 256.
// ---------------------------------------------------------------------------
__global__ __launch_bounds__(256)
void encode_mfma(const unsigned short* __restrict__ A0,
                 const unsigned short* __restrict__ Bw,
                 const float* __restrict__ bias,
                 unsigned short* __restrict__ Out) {
    __shared__ unsigned short As[128 * 32];
    __shared__ unsigned short Bs[128 * 32];
    const int tid = threadIdx.x;
    const int wave = tid >> 6, lane = tid & 63;
    const int wr = (wave >> 1) * 64, wc = (wave & 1) * 64;
    const int lq = lane >> 4, lm = lane & 15;
    const int rowBase = blockIdx.x * 128;

    floatx4 acc[4][4];
#pragma unroll
    for (int i = 0; i < 4; ++i)
#pragma unroll
        for (int j = 0; j < 4; ++j) {
            acc[i][j][0] = 0.f; acc[i][j][1] = 0.f;
            acc[i][j][2] = 0.f; acc[i][j][3] = 0.f;
        }

    for (int k0 = 0; k0 < 128; k0 += 32) {
#pragma unroll
        for (int q = 0; q < 2; ++q) {
            int id = wave * 128 + q * 64 + lane;
            int r = id >> 2, c = id & 3;
            int grow = rowBase + r;
            if (grow > NN - 1) grow = NN - 1;
            llds16(A0 + (size_t)grow * 128 + k0 + c * 8,
                   (char*)As + (size_t)(wave * 128 + q * 64) * 16);
            llds16(Bw + (size_t)r * 128 + k0 + c * 8,
                   (char*)Bs + (size_t)(wave * 128 + q * 64) * 16);
        }
        __syncthreads();
        short8 af[4], bfr[4];
#pragma unroll
        for (int i = 0; i < 4; ++i)
            af[i] = *(const short8*)&As[(wr + i * 16 + lm) * 32 + lq * 8];
#pragma unroll
        for (int j = 0; j < 4; ++j)
            bfr[j] = *(const short8*)&Bs[(wc + j * 16 + lm) * 32 + lq * 8];
#pragma unroll
        for (int i = 0; i < 4; ++i)
#pragma unroll
            for (int j = 0; j < 4; ++j)
                acc[i][j] = __builtin_amdgcn_mfma_f32_16x16x32_bf16(
                    af[i], bfr[j], acc[i][j], 0, 0, 0);
        __syncthreads();
    }
#pragma unroll
    for (int i = 0; i < 4; ++i)
#pragma unroll
        for (int r = 0; r < 4; ++r) {
            int row = rowBase + wr + i * 16 + lq * 4 + r;
            if (row >= NN) continue;
            size_t rb = (size_t)row * HID;
#pragma unroll
            for (int j = 0; j < 4; ++j) {
                int col = wc + j * 16 + lm;
                float v = acc[i][j][r] + bias[col];
                Out[rb + col] = f2bf(fmaxf(v, 0.f));
                Out[rb + col + 128] = 0;
            }
        }
}

// ---------------------------------------------------------------------------
// Fused MGU step: one block = 64 rows x all 256 cols; 4 waves (1x4),
// each wave 4x4 frags of 16x16x32 bf16.
//   phase 1: S_f = [m|h] @ [W_f;U_f]^T ; f = sigmoid(S_f + b_f) (kept in regs)
//            hf = f*h  -> HF (block-private rows)
//   phase 2: S_h = [m|hf] @ [W_h;U_h]^T
//   epilogue: h = (1-f)*h + f*tanh(S_h + b_h)   (in place)
// Bs staging: 256 cols x 32 k x 2B = 16KB -> 4 llds16 per thread per k-step.
// ---------------------------------------------------------------------------
__global__ __launch_bounds__(256)
void mgu_step(const unsigned short* __restrict__ Mm,
              const unsigned short* __restrict__ Wf,
              const unsigned short* __restrict__ Wh,
              const float* __restrict__ bf_v, const float* __restrict__ bh_v,
              unsigned short* __restrict__ H,
              unsigned short* __restrict__ HF) {
    __shared__ unsigned short As[64 * 32];    // [row][k] 4 KB
    __shared__ unsigned short Bs[256 * 32];   // [col][k] 16 KB
    const int tid = threadIdx.x;
    const int wave = tid >> 6, lane = tid & 63;
    const int wcol = wave * 64;
    const int lq = lane >> 4, lm = lane & 15;
    const int rowBase = blockIdx.x * 64;

    const int srow = tid >> 2;
    const int skk = (tid & 3) * 8;
    int garow = rowBase + srow;
    if (garow > NN - 1) garow = NN - 1;

    floatx4 accf[4][4];
#pragma unroll
    for (int i = 0; i < 4; ++i)
#pragma unroll
        for (int j = 0; j < 4; ++j) {
            accf[i][j][0] = 0.f; accf[i][j][1] = 0.f;
            accf[i][j][2] = 0.f; accf[i][j][3] = 0.f;
        }

    // ---- phase 1: gate GEMM
    for (int k0 = 0; k0 < 512; k0 += 32) {
        const unsigned short* Asrc = (k0 < 256) ? Mm : H;
        int kc = k0 & 255;
        llds16(Asrc + (size_t)garow * HID + kc + skk, (char*)As + wave * 1024);
#pragma unroll
        for (int q = 0; q < 4; ++q) {
            int id = wave * 256 + q * 64 + lane;   // 0..1023
            int n = id >> 2, bk = (id & 3) * 8;    // n: 0..255
            llds16(Wf + (size_t)n * 512 + k0 + bk,
                   (char*)Bs + (size_t)(wave * 256 + q * 64) * 16);
        }
        __syncthreads();
        short8 af[4], bfr[4];
#pragma unroll
        for (int i = 0; i < 4; ++i)
            af[i] = *(const short8*)&As[(i * 16 + lm) * 32 + lq * 8];
#pragma unroll
        for (int j = 0; j < 4; ++j)
            bfr[j] = *(const short8*)&Bs[(wcol + j * 16 + lm) * 32 + lq * 8];
#pragma unroll
        for (int i = 0; i < 4; ++i)
#pragma unroll
            for (int j = 0; j < 4; ++j)
                accf[i][j] = __builtin_amdgcn_mfma_f32_16x16x32_bf16(
                    af[i], bfr[j], accf[i][j], 0, 0, 0);
        __syncthreads();
    }

    // ---- f = sigmoid(.), hf = f*h -> HF; keep f in accf
#pragma unroll
    for (int j = 0; j < 4; ++j) {
        int col = wcol + j * 16 + lm;
        float bias = bf_v[col];
#pragma unroll
        for (int i = 0; i < 4; ++i)
#pragma unroll
            for (int r = 0; r < 4; ++r) {
                int row = rowBase + i * 16 + lq * 4 + r;
                float v = accf[i][j][r] + bias;
                float f = 1.f / (1.f + __expf(-v));
                accf[i][j][r] = f;
                if (row < NN) {
                    float hv = bf2f(H[(size_t)row * HID + col]);
                    HF[(size_t)row * HID + col] = f2bf(f * hv);
                }
            }
    }
    __threadfence();
    __syncthreads();

    // ---- phase 2: candidate GEMM
    floatx4 acch[4][4];
#pragma unroll
    for (int i = 0; i < 4; ++i)
#pragma unroll
        for (int j = 0; j < 4; ++j) {
            acch[i][j][0] = 0.f; acch[i][j][1] = 0.f;
            acch[i][j][2] = 0.f; acch[i][j][3] = 0.f;
        }
    for (int k0 = 0; k0 < 512; k0 += 32) {
        const unsigned short* Asrc = (k0 < 256) ? Mm : HF;
        int kc = k0 & 255;
        llds16(Asrc + (size_t)garow * HID + kc + skk, (char*)As + wave * 1024);
#pragma unroll
        for (int q = 0; q < 4; ++q) {
            int id = wave * 256 + q * 64 + lane;
            int n = id >> 2, bk = (id & 3) * 8;
            llds16(Wh + (size_t)n * 512 + k0 + bk,
                   (char*)Bs + (size_t)(wave * 256 + q * 64) * 16);
        }
        __syncthreads();
        short8 af[4], bfr[4];
#pragma unroll
        for (int i = 0; i < 4; ++i)
            af[i] = *(const short8*)&As[(i * 16 + lm) * 32 + lq * 8];
#pragma unroll
        for (int j = 0; j < 4; ++j)
            bfr[j] = *(const short8*)&Bs[(wcol + j * 16 + lm) * 32 + lq * 8];
#pragma unroll
        for (int i = 0; i < 4; ++i)
#pragma unroll
            for (int j = 0; j < 4; ++j)
                acch[i][j] = __builtin_amdgcn_mfma_f32_16x16x32_bf16(
                    af[i], bfr[j], acch[i][j], 0, 0, 0);
        __syncthreads();
    }

    // ---- epilogue: h = (1-f)*h + f*tanh(S_h + b_h)
#pragma unroll
    for (int j = 0; j < 4; ++j) {
        int col = wcol + j * 16 + lm;
        float bias = bh_v[col];
#pragma unroll
        for (int i = 0; i < 4; ++i)
#pragma unroll
            for (int r = 0; r < 4; ++r) {
                int row = rowBase + i * 16 + lq * 4 + r;
                if (row >= NN) continue;
                float v = acch[i][j][r] + bias;
                float xc = fminf(fmaxf(v, -12.f), 12.f);
                float e2 = __expf(2.f * xc);
                float t = (e2 - 1.f) / (e2 + 1.f);
                float f = accf[i][j][r];
                size_t a = (size_t)row * HID + col;
                float hv = bf2f(H[a]);
                H[a] = f2bf((1.f - f) * hv + f * t);
            }
    }
}

// ---------------------------------------------------------------------------
// Readout
// ---------------------------------------------------------------------------
__global__ __launch_bounds__(256)
void colmean(const unsigned short* __restrict__ h, float* __restrict__ gsum) {
    int j = threadIdx.x;
    long long n0 = (long long)blockIdx.x * 256;
    float acc = 0.0f;
    for (int n = 0; n < 256; ++n) {
        long long node = n0 + n;
        if (node < NN) acc += bf2f(h[node * HID + j]);
    }
    atomicAdd(&gsum[j], acc);
}

__global__ __launch_bounds__(256)
void final_pred(const float* __restrict__ gsum, const float* __restrict__ Wp,
                const float* __restrict__ bp, float* __restrict__ out) {
    __shared__ float s[256];
    int j = threadIdx.x;
    s[j] = gsum[j] * (1.0f / (float)NN) * Wp[j];
    __syncthreads();
    for (int ofs = 128; ofs > 0; ofs >>= 1) {
        if (j < ofs) s[j] += s[j + ofs];
        __syncthreads();
    }
    if (j == 0) out[0] = s[0] + bp[0];
}

// ---------------------------------------------------------------------------
extern "C" void kernel_launch(void* const* d_in, const int* in_sizes, int n_in,
                              void* d_out, int out_size, void* d_ws, size_t ws_size,
                              hipStream_t stream) {
    const float* x      = (const float*)d_in[0];
    const int*   ei     = (const int*)d_in[1];
    const float* W_in   = (const float*)d_in[2];
    const float* b_in   = (const float*)d_in[3];
    const float* W_f    = (const float*)d_in[4];
    const float* U_f    = (const float*)d_in[5];
    const float* b_f    = (const float*)d_in[6];
    const float* W_h    = (const float*)d_in[7];
    const float* U_h    = (const float*)d_in[8];
    const float* b_h    = (const float*)d_in[9];
    const float* W_pred = (const float*)d_in[10];
    const float* b_pred = (const float*)d_in[11];
    float* out = (float*)d_out;

    char* p = (char*)d_ws;
    auto alloc = [&](size_t bytes) {
        char* r = p;
        p += (bytes + 511) & ~(size_t)511;
        return r;
    };
    int*            cnt    = (int*)alloc((size_t)NN * 4);
    int*            cursor = (int*)alloc((size_t)NN * 4);
    int*            off    = (int*)alloc((size_t)(NN + 1) * 4);
    int*            flag   = (int*)alloc(4);
    float*          gsum   = (float*)alloc(HID * 4);
    int*            loc    = (int*)alloc((size_t)NN * 4);
    int*            bsum   = (int*)alloc((size_t)NBLK * 4);
    int*            bpre   = (int*)alloc((size_t)(NBLK + 1) * 4);
    unsigned short* wcf    = (unsigned short*)alloc((size_t)256 * 512 * 2);
    unsigned short* wch    = (unsigned short*)alloc((size_t)256 * 512 * 2);
    unsigned short* wib    = (unsigned short*)alloc((size_t)128 * 128 * 2);
    int*            csr    = (int*)alloc((size_t)NE * 4);
    unsigned short* hbuf   = (unsigned short*)alloc((size_t)NN * HID * 2);
    unsigned short* mbuf   = (unsigned short*)alloc((size_t)NN * HID * 2);
    unsigned short* hf     = (unsigned short*)alloc((size_t)NN * HID * 2);
    unsigned short* xb     = hf;   // x-bf16 (25.6MB) dead before hf first write

    detect_i64<<<1, 64, 0, stream>>>(ei, flag);
    zero_setup<<<NBLK, 256, 0, stream>>>(cnt, cursor, gsum);
    conv_weights<<<512, 256, 0, stream>>>(W_f, U_f, W_h, U_h, W_in, wcf, wch, wib);
    conv_x<<<(NN * 128 / 4 + 255) / 256, 256, 0, stream>>>(x, xb);

    count_deg<<<(NE + 255) / 256, 256, 0, stream>>>(ei, flag, cnt);
    scan_k1<<<NBLK, 256, 0, stream>>>(cnt, loc, bsum);
    scan_k2<<<1, 512, 0, stream>>>(bsum, bpre);
    scan_k3<<<NBLK, 256, 0, stream>>>(loc, bpre, off);
    fill_csr<<<(NE + 255) / 256, 256, 0, stream>>>(ei, flag, off, cursor, csr);

    encode_mfma<<<(NN + 127) / 128, 256, 0, stream>>>(xb, wib, b_in, hbuf);

    const int SBLK = (NN + 63) / 64;   // 1563
    for (int step = 0; step < 4; ++step) {
        aggregate<<<NN / 4, 256, 0, stream>>>(hbuf, off, csr, mbuf);
        mgu_step<<<SBLK, 256, 0, stream>>>(mbuf, wcf, wch, b_f, b_h, hbuf, hf);
    }

    colmean<<<NBLK, 256, 0, stream>>>(hbuf, gsum);
    final_pred<<<1, 256, 0, stream>>>(gsum, W_pred, b_pred, out);
}

// Round 6
// 2080.681 us; speedup vs baseline: 1.5106x; 1.5106x over previous
//
#include <hip/hip_runtime.h>
#include <hip/hip_bf16.h>
#include <math.h>

constexpr int NN = 100000;     // nodes
constexpr int NE = 3200000;    // edges
constexpr int HID = 256;
constexpr int NBLK = (NN + 255) / 256;        // 391
constexpr int NBUCK = 13;                     // src buckets of 8192 nodes (4MB h window)
constexpr int N13 = NN * NBUCK;               // 1,300,000 (dst-major, bucket-minor)
constexpr int NG1 = (N13 + 255) / 256;        // 5079
constexpr int NG2 = (NG1 + 255) / 256;        // 20

typedef __attribute__((ext_vector_type(8))) short short8;
typedef __attribute__((ext_vector_type(4))) float floatx4;
typedef __attribute__((ext_vector_type(8))) unsigned short ushort8v;

// ---- bf16 helpers (storage bf16, math fp32) -------------------------------
__device__ __forceinline__ float bf2f(unsigned short u) {
    unsigned int t = ((unsigned int)u) << 16;
    float f; __builtin_memcpy(&f, &t, 4); return f;
}
__device__ __forceinline__ unsigned short f2bf(float f) {
    unsigned int t; __builtin_memcpy(&t, &f, 4);
    unsigned int lsb = (t >> 16) & 1u;
    t += 0x7fffu + lsb;
    return (unsigned short)(t >> 16);
}

// async global->LDS, 16B per lane; lds base must be wave-uniform
__device__ __forceinline__ void llds16(const void* g, void* l) {
    __builtin_amdgcn_global_load_lds(
        (const __attribute__((address_space(1))) unsigned int*)g,
        (__attribute__((address_space(3))) unsigned int*)l, 16, 0, 0);
}

// ---------------------------------------------------------------------------
// Edge dtype detection (int64 vs int32 delivery)
// ---------------------------------------------------------------------------
__global__ void detect_i64(const int* __restrict__ ei, int* __restrict__ flag) {
    if (blockIdx.x == 0 && threadIdx.x == 0) {
        int z = 1;
        for (int i = 0; i < 64; ++i)
            if (ei[2 * i + 1] != 0) { z = 0; break; }
        *flag = z;
    }
}
__device__ __forceinline__ int load_edge(const int* ei, int is64, long long idx) {
    if (is64) return (int)(((const long long*)ei)[idx]);
    return ei[idx];
}

// zero the 1.3M bucket counters + gsum
__global__ void zero13(int* __restrict__ cnt13, float* __restrict__ gsum) {
    int i = blockIdx.x * 256 + threadIdx.x;
    if (i < N13) cnt13[i] = 0;
    if (i < HID) gsum[i] = 0.0f;
}

// ---------------------------------------------------------------------------
// Weight / input conversion to bf16
// ---------------------------------------------------------------------------
__global__ void conv_weights(const float* __restrict__ Wf, const float* __restrict__ Uf,
                             const float* __restrict__ Wh, const float* __restrict__ Uh,
                             const float* __restrict__ Win,
                             unsigned short* __restrict__ wcf,
                             unsigned short* __restrict__ wch,
                             unsigned short* __restrict__ wib) {
    int i = blockIdx.x * 256 + threadIdx.x;
    if (i < 256 * 512) {
        int n = i >> 9, k = i & 511;
        float vf = (k < 256) ? Wf[n * 256 + k] : Uf[n * 256 + k - 256];
        float vh = (k < 256) ? Wh[n * 256 + k] : Uh[n * 256 + k - 256];
        wcf[i] = f2bf(vf); wch[i] = f2bf(vh);
    }
    if (i < 128 * 128) wib[i] = f2bf(Win[i]);
}

__global__ void conv_x(const float* __restrict__ x, unsigned short* __restrict__ xb) {
    int i = blockIdx.x * 256 + threadIdx.x;
    if (i < NN * 128 / 4) {
        float4 v = ((const float4*)x)[i];
        ushort4 o;
        o.x = f2bf(v.x); o.y = f2bf(v.y); o.z = f2bf(v.z); o.w = f2bf(v.w);
        ((ushort4*)xb)[i] = o;
    }
}

// ---------------------------------------------------------------------------
// Bucketed CSR: counters keyed (dst*13 + (src>>13))
// ---------------------------------------------------------------------------
__global__ void count_deg13(const int* __restrict__ ei, const int* __restrict__ flag,
                            int* __restrict__ cnt13) {
    int e = blockIdx.x * 256 + threadIdx.x;
    if (e >= NE) return;
    int is64 = *flag;
    int s = load_edge(ei, is64, e);
    int d = load_edge(ei, is64, (long long)NE + e);
    s = min(max(s, 0), NN - 1);
    d = min(max(d, 0), NN - 1);
    atomicAdd(&cnt13[d * NBUCK + (s >> 13)], 1);
}

// generic per-256-block exclusive scan: loc[i]=excl-scan-in-block, bsum[b]=total
__global__ void scan_g1(const int* __restrict__ src, int* __restrict__ loc,
                        int* __restrict__ bsum, int n) {
    __shared__ int s[256];
    int b = blockIdx.x, t = threadIdx.x;
    int i = b * 256 + t;
    int v = (i < n) ? src[i] : 0;
    s[t] = v;
    __syncthreads();
    for (int ofs = 1; ofs < 256; ofs <<= 1) {
        int tv = (t >= ofs) ? s[t - ofs] : 0;
        __syncthreads();
        s[t] += tv;
        __syncthreads();
    }
    if (i < n) loc[i] = s[t] - v;
    if (t == 255) bsum[b] = s[255];
}

// serial exclusive scan of NG2 entries; total at [NG2]
__global__ void scan_tiny(int* __restrict__ a) {
    if (threadIdx.x == 0 && blockIdx.x == 0) {
        int run = 0;
        for (int i = 0; i < NG2; ++i) { int v = a[i]; a[i] = run; run += v; }
        a[NG2] = run;
    }
}

// off13[i] = loc13[i] + bsum13[i>>8] + bsum2[i>>16]; zero cursor; sentinel
__global__ void scan_fin(int* __restrict__ off13 /* = loc13 in place */,
                         const int* __restrict__ bsum13, const int* __restrict__ bsum2,
                         int* __restrict__ cursor13) {
    int i = blockIdx.x * 256 + threadIdx.x;
    if (i < N13) {
        off13[i] = off13[i] + bsum13[i >> 8] + bsum2[i >> 16];
        cursor13[i] = 0;
    }
    if (i == 0) off13[N13] = bsum2[NG2];
}

__global__ void fill_csr13(const int* __restrict__ ei, const int* __restrict__ flag,
                           const int* __restrict__ off13, int* __restrict__ cursor13,
                           int* __restrict__ csr) {
    int e = blockIdx.x * 256 + threadIdx.x;
    if (e >= NE) return;
    int is64 = *flag;
    int s = load_edge(ei, is64, e);
    int d = load_edge(ei, is64, (long long)NE + e);
    s = min(max(s, 0), NN - 1);
    d = min(max(d, 0), NN - 1);
    int key = d * NBUCK + (s >> 13);
    int p = atomicAdd(&cursor13[key], 1);
    csr[off13[key] + p] = s;
}

// ---------------------------------------------------------------------------
// Aggregation: mean of h[src] rows per node. One wave per node; half-wave per
// edge row (ushort8/lane), 4 rows in flight. Edge list is bucket-ordered by
// src>>13 so concurrent waves sweep the same 4MB h-window (L2/L3-hot).
// Node range = [off13[node*13], off13[(node+1)*13]).
// ---------------------------------------------------------------------------
__global__ __launch_bounds__(256)
void aggregate(const unsigned short* __restrict__ h, const int* __restrict__ off13,
               const int* __restrict__ csr, unsigned short* __restrict__ m) {
    int node = blockIdx.x * 4 + (threadIdx.x >> 6);
    int lane = threadIdx.x & 63;
    int half = lane >> 5;
    int fl = lane & 31;
    int e0 = off13[node * NBUCK], e1 = off13[(node + 1) * NBUCK];
    float a0[8], a1[8];
#pragma unroll
    for (int k = 0; k < 8; ++k) { a0[k] = 0.f; a1[k] = 0.f; }
    int e = e0;
    for (; e + 8 <= e1; e += 8) {
        int s0 = csr[e + half];
        int s1 = csr[e + 2 + half];
        int s2 = csr[e + 4 + half];
        int s3 = csr[e + 6 + half];
        ushort8v v0 = *(const ushort8v*)(h + (size_t)s0 * HID + fl * 8);
        ushort8v v1 = *(const ushort8v*)(h + (size_t)s1 * HID + fl * 8);
        ushort8v v2 = *(const ushort8v*)(h + (size_t)s2 * HID + fl * 8);
        ushort8v v3 = *(const ushort8v*)(h + (size_t)s3 * HID + fl * 8);
#pragma unroll
        for (int k = 0; k < 8; ++k) {
            a0[k] += bf2f(v0[k]); a1[k] += bf2f(v1[k]);
            a0[k] += bf2f(v2[k]); a1[k] += bf2f(v3[k]);
        }
    }
    for (; e + 2 <= e1; e += 2) {
        int s0 = csr[e + half];
        ushort8v v0 = *(const ushort8v*)(h + (size_t)s0 * HID + fl * 8);
#pragma unroll
        for (int k = 0; k < 8; ++k) a0[k] += bf2f(v0[k]);
    }
    if (e < e1 && half == 0) {
        int s0 = csr[e];
        ushort8v v0 = *(const ushort8v*)(h + (size_t)s0 * HID + fl * 8);
#pragma unroll
        for (int k = 0; k < 8; ++k) a0[k] += bf2f(v0[k]);
    }
#pragma unroll
    for (int k = 0; k < 8; ++k) a0[k] += a1[k];
#pragma unroll
    for (int k = 0; k < 8; ++k) a0[k] += __shfl(a0[k], lane ^ 32, 64);
    float inv = 1.0f / (float)max(e1 - e0, 1);
    if (half == 0) {
        ushort8v o;
#pragma unroll
        for (int k = 0; k < 8; ++k) o[k] = f2bf(a0[k] * inv);
        *(ushort8v*)(m + (size_t)node * HID + fl * 8) = o;
    }
}

// ---------------------------------------------------------------------------
// MFMA GEMM (round-3 proven structure), 128x128 tile, 4 waves (2x2),
// each wave 4x4 of 16x16x32 bf16. A=[A0|A1] along K. B rows = weight rows.
// MODE 0: encode  K=128: Out = relu(v+bias) cols 0..127; cols 128..255 = 0
// MODE 1: gate    K=512: f = sigmoid(v+bias) -> Ff;  HF = f * Hh
// MODE 2: cand    K=512: Out(=Hh) = (1-f)*h + f*tanh(v+bias)   (in place)
// ---------------------------------------------------------------------------
template <int MODE>
__global__ __launch_bounds__(256)
void gemm_mfma(const unsigned short* __restrict__ A0,
               const unsigned short* __restrict__ A1,
               const unsigned short* __restrict__ Bw,
               const float* __restrict__ bias,
               const unsigned short* Hh,
               unsigned short* Ff,
               unsigned short* HF,
               unsigned short* Out) {
    constexpr int KTOT = (MODE == 0) ? 128 : 512;
    constexpr int ASTR = (MODE == 0) ? 256 : 512;    // bytes per A row
    constexpr int BSTR = (MODE == 0) ? 256 : 1024;   // bytes per B row

    __shared__ unsigned short As[128 * 32];
    __shared__ unsigned short Bs[128 * 32];

    const int tid = threadIdx.x;
    const int wave = tid >> 6, lane = tid & 63;
    const int wr = (wave >> 1) * 64, wc = (wave & 1) * 64;
    const int lq = lane >> 4, lm = lane & 15;
    const int rowBase = blockIdx.x * 128;
    const int colBase = blockIdx.y * 128;

    floatx4 acc[4][4];
#pragma unroll
    for (int i = 0; i < 4; ++i)
#pragma unroll
        for (int j = 0; j < 4; ++j) {
            acc[i][j][0] = 0.f; acc[i][j][1] = 0.f;
            acc[i][j][2] = 0.f; acc[i][j][3] = 0.f;
        }

    for (int k0 = 0; k0 < KTOT; k0 += 32) {
        const unsigned short* Ak;
        int kc;
        if (MODE != 0 && k0 >= 256) { Ak = A1; kc = k0 - 256; }
        else                         { Ak = A0; kc = k0; }
#pragma unroll
        for (int q = 0; q < 2; ++q) {
            int id = wave * 128 + q * 64 + lane;
            int r = id >> 2, c = id & 3;
            int grow = rowBase + r;
            if (grow > NN - 1) grow = NN - 1;
            const char* ga = (const char*)Ak + (size_t)grow * ASTR + kc * 2 + c * 16;
            char* la = (char*)As + (size_t)(wave * 128 + q * 64) * 16;
            llds16(ga, la);
            const char* gb = (const char*)Bw + (size_t)(colBase + r) * BSTR + k0 * 2 + c * 16;
            char* lb = (char*)Bs + (size_t)(wave * 128 + q * 64) * 16;
            llds16(gb, lb);
        }
        __syncthreads();
        short8 af[4], bf_[4];
#pragma unroll
        for (int i = 0; i < 4; ++i)
            af[i] = *(const short8*)&As[(wr + i * 16 + lm) * 32 + lq * 8];
#pragma unroll
        for (int j = 0; j < 4; ++j)
            bf_[j] = *(const short8*)&Bs[(wc + j * 16 + lm) * 32 + lq * 8];
#pragma unroll
        for (int i = 0; i < 4; ++i)
#pragma unroll
            for (int j = 0; j < 4; ++j)
                acc[i][j] = __builtin_amdgcn_mfma_f32_16x16x32_bf16(
                    af[i], bf_[j], acc[i][j], 0, 0, 0);
        __syncthreads();
    }

    // epilogue
#pragma unroll
    for (int i = 0; i < 4; ++i) {
#pragma unroll
        for (int r = 0; r < 4; ++r) {
            int row = rowBase + wr + i * 16 + lq * 4 + r;
            if (row >= NN) continue;
            size_t rb = (size_t)row * HID;
#pragma unroll
            for (int j = 0; j < 4; ++j) {
                int col = colBase + wc + j * 16 + lm;
                float v = acc[i][j][r] + bias[col];
                if (MODE == 0) {
                    Out[rb + col] = f2bf(fmaxf(v, 0.f));
                    Out[rb + col + 128] = 0;
                } else if (MODE == 1) {
                    float f = 1.f / (1.f + __expf(-v));
                    float hv = bf2f(Hh[rb + col]);
                    Ff[rb + col] = f2bf(f);
                    HF[rb + col] = f2bf(f * hv);
                } else {
                    float xc = fminf(fmaxf(v, -12.f), 12.f);
                    float e2 = __expf(2.f * xc);
                    float t = (e2 - 1.f) / (e2 + 1.f);
                    float f = bf2f(Ff[rb + col]);
                    float hv = bf2f(Hh[rb + col]);
                    Out[rb + col] = f2bf((1.f - f) * hv + f * t);
                }
            }
        }
    }
}

// ---------------------------------------------------------------------------
// Readout
// ---------------------------------------------------------------------------
__global__ __launch_bounds__(256)
void colmean(const unsigned short* __restrict__ h, float* __restrict__ gsum) {
    int j = threadIdx.x;
    long long n0 = (long long)blockIdx.x * 256;
    float acc = 0.0f;
    for (int n = 0; n < 256; ++n) {
        long long node = n0 + n;
        if (node < NN) acc += bf2f(h[node * HID + j]);
    }
    atomicAdd(&gsum[j], acc);
}

__global__ __launch_bounds__(256)
void final_pred(const float* __restrict__ gsum, const float* __restrict__ Wp,
                const float* __restrict__ bp, float* __restrict__ out) {
    __shared__ float s[256];
    int j = threadIdx.x;
    s[j] = gsum[j] * (1.0f / (float)NN) * Wp[j];
    __syncthreads();
    for (int ofs = 128; ofs > 0; ofs >>= 1) {
        if (j < ofs) s[j] += s[j + ofs];
        __syncthreads();
    }
    if (j == 0) out[0] = s[0] + bp[0];
}

// ---------------------------------------------------------------------------
extern "C" void kernel_launch(void* const* d_in, const int* in_sizes, int n_in,
                              void* d_out, int out_size, void* d_ws, size_t ws_size,
                              hipStream_t stream) {
    const float* x      = (const float*)d_in[0];
    const int*   ei     = (const int*)d_in[1];
    const float* W_in   = (const float*)d_in[2];
    const float* b_in   = (const float*)d_in[3];
    const float* W_f    = (const float*)d_in[4];
    const float* U_f    = (const float*)d_in[5];
    const float* b_f    = (const float*)d_in[6];
    const float* W_h    = (const float*)d_in[7];
    const float* U_h    = (const float*)d_in[8];
    const float* b_h    = (const float*)d_in[9];
    const float* W_pred = (const float*)d_in[10];
    const float* b_pred = (const float*)d_in[11];
    float* out = (float*)d_out;

    char* p = (char*)d_ws;
    auto alloc = [&](size_t bytes) {
        char* r = p;
        p += (bytes + 511) & ~(size_t)511;
        return r;
    };
    int*            flag   = (int*)alloc(4);
    float*          gsum   = (float*)alloc(HID * 4);
    unsigned short* wcf    = (unsigned short*)alloc((size_t)256 * 512 * 2);
    unsigned short* wch    = (unsigned short*)alloc((size_t)256 * 512 * 2);
    unsigned short* wib    = (unsigned short*)alloc((size_t)128 * 128 * 2);
    int*            cnt13  = (int*)alloc((size_t)N13 * 4);        // -> cursor13
    int*            loc13  = (int*)alloc((size_t)(N13 + 1) * 4);  // -> off13
    int*            bsum13 = (int*)alloc((size_t)NG1 * 4);
    int*            bsum2  = (int*)alloc((size_t)(NG2 + 1) * 4);
    int*            csr    = (int*)alloc((size_t)NE * 4);
    unsigned short* hbuf   = (unsigned short*)alloc((size_t)NN * HID * 2);
    unsigned short* mbuf   = (unsigned short*)alloc((size_t)NN * HID * 2);
    unsigned short* fbuf   = (unsigned short*)alloc((size_t)NN * HID * 2);
    unsigned short* hf     = (unsigned short*)alloc((size_t)NN * HID * 2);
    unsigned short* xb     = hf;   // x-bf16 (25.6MB) dead before hf first write
    int*            cursor13 = cnt13;   // reuse: zeroed by scan_fin
    int*            off13    = loc13;   // scan_fin finalizes in place

    detect_i64<<<1, 64, 0, stream>>>(ei, flag);
    zero13<<<NG1, 256, 0, stream>>>(cnt13, gsum);
    conv_weights<<<512, 256, 0, stream>>>(W_f, U_f, W_h, U_h, W_in, wcf, wch, wib);
    conv_x<<<(NN * 128 / 4 + 255) / 256, 256, 0, stream>>>(x, xb);

    count_deg13<<<(NE + 255) / 256, 256, 0, stream>>>(ei, flag, cnt13);
    scan_g1<<<NG1, 256, 0, stream>>>(cnt13, loc13, bsum13, N13);
    scan_g1<<<NG2, 256, 0, stream>>>(bsum13, bsum13, bsum2, NG1);
    scan_tiny<<<1, 64, 0, stream>>>(bsum2);
    scan_fin<<<NG1, 256, 0, stream>>>(off13, bsum13, bsum2, cursor13);
    fill_csr13<<<(NE + 255) / 256, 256, 0, stream>>>(ei, flag, off13, cursor13, csr);

    const int MBLK = (NN + 127) / 128;   // 782
    gemm_mfma<0><<<dim3(MBLK, 1), 256, 0, stream>>>(
        xb, nullptr, wib, b_in, nullptr, nullptr, nullptr, hbuf);

    for (int step = 0; step < 4; ++step) {
        aggregate<<<NN / 4, 256, 0, stream>>>(hbuf, off13, csr, mbuf);
        gemm_mfma<1><<<dim3(MBLK, 2), 256, 0, stream>>>(
            mbuf, hbuf, wcf, b_f, hbuf, fbuf, hf, nullptr);
        gemm_mfma<2><<<dim3(MBLK, 2), 256, 0, stream>>>(
            mbuf, hf, wch, b_h, hbuf, fbuf, nullptr, hbuf);
    }

    colmean<<<NBLK, 256, 0, stream>>>(hbuf, gsum);
    final_pred<<<1, 256, 0, stream>>>(gsum, W_pred, b_pred, out);
}